// Round 2
// baseline (953.805 us; speedup 1.0000x reference)
//
#include <hip/hip_runtime.h>
#include <hip/hip_bf16.h>

// Problem constants: T=512 tokens, D=2048 hidden, E=64 experts, K=8 top-k, F=768.
#define T_TOK 512
#define D_DIM 2048
#define E_NUM 64
#define K_TOP 8
#define F_DIM 768

typedef __bf16 bf16x8 __attribute__((ext_vector_type(8)));
typedef float  f32x4  __attribute__((ext_vector_type(4)));

// ---------------- workspace layout (bytes) ----------------
// cnt    : int[64]            @ 0
// ids    : int[64*512]        @ 4096
// pair_w : float[4096]        @ 139264
// H      : bf16[4096*768]     @ 262144
// Y      : bf16[4096*2048]    @ 8388608
#define WS_IDS   4096
#define WS_PW    139264
#define WS_H     262144
#define WS_Y     8388608

__global__ void zero_cnt_kernel(int* __restrict__ cnt) {
    if (threadIdx.x < E_NUM) cnt[threadIdx.x] = 0;
}

// ---------------- router: logits -> softmax -> top-8 -> renorm ----------------
__global__ __launch_bounds__(256) void router_kernel(
        const float* __restrict__ x, const float* __restrict__ gw,
        float* __restrict__ pair_w, int* __restrict__ cnt, int* __restrict__ ids) {
    const int t   = blockIdx.x;
    const int tid = threadIdx.x;
    const int e   = tid & 63;
    const int c   = tid >> 6;
    const float* xr = x + (size_t)t * D_DIM;
    const int k0 = c * (D_DIM / 4);
    float s = 0.f;
    #pragma unroll 8
    for (int k = 0; k < D_DIM / 4; k++) {
        s += xr[k0 + k] * gw[(size_t)(k0 + k) * E_NUM + e];
    }
    __shared__ float part[4][64];
    part[c][e] = s;
    __syncthreads();
    if (tid < 64) {  // first wave only; lane == e
        float logit = part[0][e] + part[1][e] + part[2][e] + part[3][e];
        float cur = logit;
        float selV[8]; int selE[8];
        #pragma unroll
        for (int i = 0; i < 8; i++) {
            float bv = cur; int bi = e;
            #pragma unroll
            for (int off = 32; off > 0; off >>= 1) {
                float ov = __shfl_xor(bv, off);
                int   oi = __shfl_xor(bi, off);
                if (ov > bv || (ov == bv && oi < bi)) { bv = ov; bi = oi; }
            }
            selV[i] = bv; selE[i] = bi;
            if (e == bi) cur = -INFINITY;
        }
        const float m = selV[0];
        float sum = 0.f;
        #pragma unroll
        for (int i = 0; i < 8; i++) sum += __expf(selV[i] - m);
        float myW = 0.f; int myE = 0;
        #pragma unroll
        for (int i = 0; i < 8; i++) {
            if (e == i) { myW = __expf(selV[i] - m) / sum; myE = selE[i]; }
        }
        if (e < 8) {
            pair_w[t * K_TOP + e] = myW;
            int pos = atomicAdd(&cnt[myE], 1);
            ids[myE * T_TOK + pos] = t * K_TOP + e;  // token = id>>3
        }
    }
}

// ---------------- mlp1: H[pair] = silu(X@Wg) * (X@Wu) ----------------
// Barrier-free, LDS-free. BM=64 (4 m-frags/wave), BN=64 (wave owns 16 f-cols).
// A fragments loaded per-wave straight from global (L1/L2 serves the 4x wave
// redundancy; X is 4 MB, cache-resident). B per-lane k-gather dwords (each
// 16-lane group = one full 64B line). No __syncthreads in the loop -> loads
// pipeline freely across k-steps; BW-bound by weight streaming.
// MFMA maps (16x16x32 bf16): A[m][k]: m=lane&15, k=8*(lane>>4)+i
//                            B[k][n]: n=lane&15, k=8*(lane>>4)+i
//                            D[row][col]: col=lane&15, row=4*(lane>>4)+r
__global__ __launch_bounds__(256, 3) void mlp1_kernel(
        const float* __restrict__ x,
        const float* __restrict__ w_gate, const float* __restrict__ w_up,
        const int* __restrict__ cnt, const int* __restrict__ ids,
        __bf16* __restrict__ H) {
    const int e     = blockIdx.z;
    const int mtile = blockIdx.y;
    const int ftile = blockIdx.x;   // 12 tiles of 64
    const int n = cnt[e];
    if (mtile * 64 >= n) return;

    const int tid  = threadIdx.x;
    const int lane = tid & 63;
    const int w    = tid >> 6;
    const int g16  = lane >> 4;     // 0..3
    const int l16  = lane & 15;

    // A row pointers, pre-offset by k0 = 8*g16 (float4 granularity)
    const float4* ar[4];
    #pragma unroll
    for (int m = 0; m < 4; m++) {
        const int p   = mtile * 64 + m * 16 + l16;
        const int tok = (p < n) ? (ids[e * T_TOK + p] >> 3) : 0;
        ar[m] = (const float4*)(x + (size_t)tok * D_DIM) + g16 * 2;
    }
    const int fcol = ftile * 64 + w * 16 + l16;
    const size_t bbase = (size_t)e * D_DIM * F_DIM + (size_t)(g16 * 8) * F_DIM + fcol;
    const float* bg = w_gate + bbase;
    const float* bu = w_up   + bbase;

    f32x4 accg[4], accu[4];
    #pragma unroll
    for (int m = 0; m < 4; m++) {
        accg[m][0]=0.f; accg[m][1]=0.f; accg[m][2]=0.f; accg[m][3]=0.f;
        accu[m][0]=0.f; accu[m][1]=0.f; accu[m][2]=0.f; accu[m][3]=0.f;
    }

    #pragma unroll 2
    for (int ks = 0; ks < D_DIM / 32; ks++) {
        // B gathers (16 dwords)
        float bgv[8], buv[8];
        #pragma unroll
        for (int i = 0; i < 8; i++) {
            const int off = (ks * 32 + i) * F_DIM;
            bgv[i] = bg[off];
            buv[i] = bu[off];
        }
        // A fragments (8 float4)
        float4 a0[4], a1[4];
        #pragma unroll
        for (int m = 0; m < 4; m++) {
            a0[m] = ar[m][ks * 8];
            a1[m] = ar[m][ks * 8 + 1];
        }
        // convert
        bf16x8 bgf, buf8, af[4];
        #pragma unroll
        for (int i = 0; i < 8; i++) { bgf[i] = (__bf16)bgv[i]; buf8[i] = (__bf16)buv[i]; }
        #pragma unroll
        for (int m = 0; m < 4; m++) {
            af[m][0]=(__bf16)a0[m].x; af[m][1]=(__bf16)a0[m].y;
            af[m][2]=(__bf16)a0[m].z; af[m][3]=(__bf16)a0[m].w;
            af[m][4]=(__bf16)a1[m].x; af[m][5]=(__bf16)a1[m].y;
            af[m][6]=(__bf16)a1[m].z; af[m][7]=(__bf16)a1[m].w;
        }
        #pragma unroll
        for (int m = 0; m < 4; m++) {
            accg[m] = __builtin_amdgcn_mfma_f32_16x16x32_bf16(af[m], bgf,  accg[m], 0, 0, 0);
            accu[m] = __builtin_amdgcn_mfma_f32_16x16x32_bf16(af[m], buf8, accu[m], 0, 0, 0);
        }
    }

    // epilogue: h = silu(g)*u -> H[rid][fcol]
    #pragma unroll
    for (int m = 0; m < 4; m++) {
        #pragma unroll
        for (int r = 0; r < 4; r++) {
            const int p = mtile * 64 + m * 16 + g16 * 4 + r;
            if (p < n) {
                const int rid = ids[e * T_TOK + p];
                const float g = accg[m][r], u = accu[m][r];
                const float h = (g / (1.f + __expf(-g))) * u;
                H[(size_t)rid * F_DIM + fcol] = (__bf16)h;
            }
        }
    }
}

// ---------------- mlp2: Y[pair] = H @ Wd ----------------
// Same barrier-free structure. A = H rows (bf16, one uint4 per frag).
__global__ __launch_bounds__(256, 3) void mlp2_kernel(
        const __bf16* __restrict__ H, const float* __restrict__ w_down,
        const int* __restrict__ cnt, const int* __restrict__ ids,
        __bf16* __restrict__ Y) {
    const int e     = blockIdx.z;
    const int mtile = blockIdx.y;
    const int dtile = blockIdx.x;   // 32 tiles of 64
    const int n = cnt[e];
    if (mtile * 64 >= n) return;

    const int tid  = threadIdx.x;
    const int lane = tid & 63;
    const int w    = tid >> 6;
    const int g16  = lane >> 4;
    const int l16  = lane & 15;

    const uint4* hr[4];
    #pragma unroll
    for (int m = 0; m < 4; m++) {
        const int p   = mtile * 64 + m * 16 + l16;
        const int rid = (p < n) ? ids[e * T_TOK + p] : 0;
        hr[m] = (const uint4*)(H + (size_t)rid * F_DIM) + g16;  // k0 = 8*g16
    }
    const int dcol = dtile * 64 + w * 16 + l16;
    const float* bd = w_down + (size_t)e * F_DIM * D_DIM + (size_t)(g16 * 8) * D_DIM + dcol;

    f32x4 acc[4];
    #pragma unroll
    for (int m = 0; m < 4; m++) { acc[m][0]=0.f; acc[m][1]=0.f; acc[m][2]=0.f; acc[m][3]=0.f; }

    #pragma unroll 2
    for (int ks = 0; ks < F_DIM / 32; ks++) {
        float bdv[8];
        #pragma unroll
        for (int i = 0; i < 8; i++) bdv[i] = bd[(ks * 32 + i) * D_DIM];
        uint4 av[4];
        #pragma unroll
        for (int m = 0; m < 4; m++) av[m] = hr[m][ks * 4];
        bf16x8 bdf;
        #pragma unroll
        for (int i = 0; i < 8; i++) bdf[i] = (__bf16)bdv[i];
        #pragma unroll
        for (int m = 0; m < 4; m++) {
            acc[m] = __builtin_amdgcn_mfma_f32_16x16x32_bf16(
                __builtin_bit_cast(bf16x8, av[m]), bdf, acc[m], 0, 0, 0);
        }
    }

    #pragma unroll
    for (int m = 0; m < 4; m++) {
        #pragma unroll
        for (int r = 0; r < 4; r++) {
            const int p = mtile * 64 + m * 16 + g16 * 4 + r;
            if (p < n) {
                const int rid = ids[e * T_TOK + p];
                Y[(size_t)rid * D_DIM + dcol] = (__bf16)acc[m][r];
            }
        }
    }
}

// ---------------- combine: out[t] = sum_k w[t,k] * Y[t*8+k] ----------------
__global__ __launch_bounds__(256) void combine_kernel(
        const __bf16* __restrict__ Y, const float* __restrict__ pw,
        float* __restrict__ out) {
    const int t   = blockIdx.x;
    const int tid = threadIdx.x;
    const int d0  = tid * 8;
    float acc[8];
    #pragma unroll
    for (int j = 0; j < 8; j++) acc[j] = 0.f;
    #pragma unroll
    for (int k = 0; k < K_TOP; k++) {
        const float wgt = pw[t * K_TOP + k];
        bf16x8 v = *(const bf16x8*)(Y + (size_t)(t * K_TOP + k) * D_DIM + d0);
        #pragma unroll
        for (int j = 0; j < 8; j++) acc[j] += wgt * (float)v[j];
    }
    #pragma unroll
    for (int j = 0; j < 8; j++) out[(size_t)t * D_DIM + d0 + j] = acc[j];
}

extern "C" void kernel_launch(void* const* d_in, const int* in_sizes, int n_in,
                              void* d_out, int out_size, void* d_ws, size_t ws_size,
                              hipStream_t stream) {
    const float* x      = (const float*)d_in[0];
    const float* gw     = (const float*)d_in[1];
    const float* w_gate = (const float*)d_in[2];
    const float* w_up   = (const float*)d_in[3];
    const float* w_down = (const float*)d_in[4];
    float* out = (float*)d_out;

    char* ws = (char*)d_ws;
    int*    cnt = (int*)(ws);
    int*    ids = (int*)(ws + WS_IDS);
    float*  pw  = (float*)(ws + WS_PW);
    __bf16* H   = (__bf16*)(ws + WS_H);
    __bf16* Y   = (__bf16*)(ws + WS_Y);

    zero_cnt_kernel<<<1, 64, 0, stream>>>(cnt);
    router_kernel<<<T_TOK, 256, 0, stream>>>(x, gw, pw, cnt, ids);
    // y-dim 8 covers any routing skew (n_e <= 512); empty tiles exit on cnt read.
    mlp1_kernel<<<dim3(F_DIM / 64, 8, E_NUM), 256, 0, stream>>>(x, w_gate, w_up, cnt, ids, H);
    mlp2_kernel<<<dim3(D_DIM / 64, 8, E_NUM), 256, 0, stream>>>(H, w_down, cnt, ids, Y);
    combine_kernel<<<T_TOK, 256, 0, stream>>>(Y, pw, out);
}